// Round 1
// baseline (8304.640 us; speedup 1.0000x reference)
//
#include <hip/hip_runtime.h>
#include <hip/hip_bf16.h>

#define HIDDEN 128

// ---------------------------------------------------------------------------
// K0: S0 = item_emb ; S1 = S2 = S3 = 0   (all float4 vectorized, grid-stride)
// ---------------------------------------------------------------------------
__global__ void init_kernel(const float4* __restrict__ emb,
                            float4* __restrict__ s0,
                            float4* __restrict__ s1,
                            float4* __restrict__ s2,
                            float4* __restrict__ s3,
                            size_t n4) {
    size_t stride = (size_t)gridDim.x * blockDim.x;
    float4 zero = make_float4(0.f, 0.f, 0.f, 0.f);
    for (size_t i = (size_t)blockIdx.x * blockDim.x + threadIdx.x; i < n4; i += stride) {
        s0[i] = emb[i];
        s1[i] = zero;
        s2[i] = zero;
        s3[i] = zero;
    }
}

// ---------------------------------------------------------------------------
// K1: COO spmm via atomic scatter. 32 threads per edge, float4 per thread.
//     y[rows[e]] += vals[e] * x[cols[e]]
// ---------------------------------------------------------------------------
__global__ void spmm_atomic(const int* __restrict__ rows,
                            const int* __restrict__ cols,
                            const float* __restrict__ vals,
                            const float* __restrict__ x,
                            float* __restrict__ y,
                            int n_edges) {
    int t = blockIdx.x * blockDim.x + threadIdx.x;
    int e = t >> 5;          // 32 threads per edge
    int lane = t & 31;       // covers 128 floats as 32 x float4
    if (e >= n_edges) return;

    int r = rows[e];
    int c = cols[e];
    float v = vals[e];

    const float4* xp = (const float4*)(x + (size_t)c * HIDDEN);
    float4 xv = xp[lane];

    float* yp = y + (size_t)r * HIDDEN + (size_t)lane * 4;
    atomicAdd(yp + 0, v * xv.x);
    atomicAdd(yp + 1, v * xv.y);
    atomicAdd(yp + 2, v * xv.z);
    atomicAdd(yp + 3, v * xv.w);
}

// ---------------------------------------------------------------------------
// K2: total = S0 + S1 + S2 + S3
// ---------------------------------------------------------------------------
__global__ void total_kernel(const float4* __restrict__ s0,
                             const float4* __restrict__ s1,
                             const float4* __restrict__ s2,
                             const float4* __restrict__ s3,
                             float4* __restrict__ t,
                             size_t n4) {
    size_t stride = (size_t)gridDim.x * blockDim.x;
    for (size_t i = (size_t)blockIdx.x * blockDim.x + threadIdx.x; i < n4; i += stride) {
        float4 a = s0[i], b = s1[i], c = s2[i], d = s3[i];
        float4 o;
        o.x = a.x + b.x + c.x + d.x;
        o.y = a.y + b.y + c.y + d.y;
        o.z = a.z + b.z + c.z + d.z;
        o.w = a.w + b.w + c.w + d.w;
        t[i] = o;
    }
}

extern "C" void kernel_launch(void* const* d_in, const int* in_sizes, int n_in,
                              void* d_out, int out_size, void* d_ws, size_t ws_size,
                              hipStream_t stream) {
    const float* item_emb = (const float*)d_in[0];
    const int*   adj_rows = (const int*)d_in[1];
    const int*   adj_cols = (const int*)d_in[2];
    const float* adj_vals = (const float*)d_in[3];
    // num_layers (d_in[4]) is fixed at 3 by setup; hardcoded below.

    const size_t NH = (size_t)in_sizes[0];      // N * 128 = 12,800,000
    const int    E  = in_sizes[1];              // 1,600,000
    const size_t n4 = NH / 4;

    // d_out layout: [ total (NH) | S0 (NH) | S1 (NH) | S2 (NH) | S3 (NH) ]
    float* T  = (float*)d_out;
    float* S0 = T + NH;
    float* S1 = S0 + NH;
    float* S2 = S1 + NH;
    float* S3 = S2 + NH;

    // K0: copy layer0, zero layers 1..3
    {
        int block = 256;
        int grid = (int)((n4 + block - 1) / block);
        if (grid > 65535) grid = 65535;
        init_kernel<<<grid, block, 0, stream>>>((const float4*)item_emb,
                                                (float4*)S0, (float4*)S1,
                                                (float4*)S2, (float4*)S3, n4);
    }

    // K1 x3: spmm layers
    {
        int block = 256;                        // 8 edges per block
        int grid = (E * 32 + block - 1) / block;
        spmm_atomic<<<grid, block, 0, stream>>>(adj_rows, adj_cols, adj_vals, S0, S1, E);
        spmm_atomic<<<grid, block, 0, stream>>>(adj_rows, adj_cols, adj_vals, S1, S2, E);
        spmm_atomic<<<grid, block, 0, stream>>>(adj_rows, adj_cols, adj_vals, S2, S3, E);
    }

    // K2: total
    {
        int block = 256;
        int grid = (int)((n4 + block - 1) / block);
        if (grid > 65535) grid = 65535;
        total_kernel<<<grid, block, 0, stream>>>((const float4*)S0, (const float4*)S1,
                                                 (const float4*)S2, (const float4*)S3,
                                                 (float4*)T, n4);
    }
}

// Round 2
// 1033.037 us; speedup vs baseline: 8.0391x; 8.0391x over previous
//
#include <hip/hip_runtime.h>
#include <hip/hip_bf16.h>

#define HIDDEN 128
#define SCAN_THREADS 1024

// ---------------------------------------------------------------------------
// CSR build step 1: zero row counters
// ---------------------------------------------------------------------------
__global__ void zero_counts(int* __restrict__ counts, int n) {
    int i = blockIdx.x * blockDim.x + threadIdx.x;
    int stride = gridDim.x * blockDim.x;
    for (; i < n; i += stride) counts[i] = 0;
}

// CSR build step 2: histogram of row degrees
__global__ void hist_kernel(const int* __restrict__ rows, int* __restrict__ counts, int E) {
    int i = blockIdx.x * blockDim.x + threadIdx.x;
    int stride = gridDim.x * blockDim.x;
    for (; i < E; i += stride) atomicAdd(&counts[rows[i]], 1);
}

// CSR build step 3: single-block exclusive scan of counts -> row_ptr, cursor
__global__ void scan_kernel(const int* __restrict__ counts,
                            int* __restrict__ row_ptr,
                            int* __restrict__ cursor,
                            int n) {
    __shared__ int sdata[SCAN_THREADS];
    int t = threadIdx.x;
    int chunk = (n + SCAN_THREADS - 1) / SCAN_THREADS;
    int lo = t * chunk;
    int hi = min(lo + chunk, n);

    int mysum = 0;
    for (int i = lo; i < hi; ++i) mysum += counts[i];
    sdata[t] = mysum;
    __syncthreads();

    // Hillis-Steele inclusive scan over 1024 partials
    for (int off = 1; off < SCAN_THREADS; off <<= 1) {
        int v = 0;
        if (t >= off) v = sdata[t - off];
        __syncthreads();
        if (t >= off) sdata[t] += v;
        __syncthreads();
    }

    int running = sdata[t] - mysum;   // exclusive prefix for this thread's chunk
    for (int i = lo; i < hi; ++i) {
        row_ptr[i] = running;
        cursor[i] = running;
        running += counts[i];
    }
    if (t == SCAN_THREADS - 1) row_ptr[n] = sdata[SCAN_THREADS - 1];
}

// CSR build step 4: scatter edges into CSR slots
__global__ void scatter_kernel(const int* __restrict__ rows,
                               const int* __restrict__ cols,
                               const float* __restrict__ vals,
                               int* __restrict__ cursor,
                               int* __restrict__ csr_col,
                               float* __restrict__ csr_val,
                               int E) {
    int i = blockIdx.x * blockDim.x + threadIdx.x;
    int stride = gridDim.x * blockDim.x;
    for (; i < E; i += stride) {
        int r = rows[i];
        int pos = atomicAdd(&cursor[r], 1);
        csr_col[pos] = cols[i];
        csr_val[pos] = vals[i];
    }
}

// ---------------------------------------------------------------------------
// S0 = item_emb (float4 copy)
// ---------------------------------------------------------------------------
__global__ void copy_kernel(const float4* __restrict__ src, float4* __restrict__ dst, size_t n4) {
    size_t stride = (size_t)gridDim.x * blockDim.x;
    for (size_t i = (size_t)blockIdx.x * blockDim.x + threadIdx.x; i < n4; i += stride)
        dst[i] = src[i];
}

// ---------------------------------------------------------------------------
// CSR SpMM: one wave (64 lanes) per row; each lane owns float2 of hidden dim.
// Edge (col,val) loaded cooperatively, broadcast via __shfl. No atomics.
// FUSE_TOTAL: also writes t = s0 + s1 + s2 + acc (layer 3 only).
// ---------------------------------------------------------------------------
template <bool FUSE_TOTAL>
__global__ void spmm_csr(const int* __restrict__ row_ptr,
                         const int* __restrict__ csr_col,
                         const float* __restrict__ csr_val,
                         const float* __restrict__ x,
                         float* __restrict__ y,
                         const float* __restrict__ s0,
                         const float* __restrict__ s1,
                         const float* __restrict__ s2,
                         float* __restrict__ t_out,
                         int n_rows) {
    int wave = (int)(((size_t)blockIdx.x * blockDim.x + threadIdx.x) >> 6);
    int lane = threadIdx.x & 63;
    if (wave >= n_rows) return;

    int start = row_ptr[wave];
    int end   = row_ptr[wave + 1];

    const float2* X = (const float2*)x;
    float2 acc = make_float2(0.f, 0.f);

    for (int base = start; base < end; base += 64) {
        int idx = base + lane;
        int c = 0;
        float v = 0.f;
        if (idx < end) { c = csr_col[idx]; v = csr_val[idx]; }
        int n = min(64, end - base);
        for (int j = 0; j < n; ++j) {
            int   cj = __shfl(c, j);
            float vj = __shfl(v, j);
            float2 xv = X[(size_t)cj * 64 + lane];
            acc.x += vj * xv.x;
            acc.y += vj * xv.y;
        }
    }

    size_t out_idx = (size_t)wave * 64 + lane;
    ((float2*)y)[out_idx] = acc;

    if (FUSE_TOTAL) {
        float2 a = ((const float2*)s0)[out_idx];
        float2 b = ((const float2*)s1)[out_idx];
        float2 c2 = ((const float2*)s2)[out_idx];
        float2 o;
        o.x = a.x + b.x + c2.x + acc.x;
        o.y = a.y + b.y + c2.y + acc.y;
        ((float2*)t_out)[out_idx] = o;
    }
}

extern "C" void kernel_launch(void* const* d_in, const int* in_sizes, int n_in,
                              void* d_out, int out_size, void* d_ws, size_t ws_size,
                              hipStream_t stream) {
    const float* item_emb = (const float*)d_in[0];
    const int*   adj_rows = (const int*)d_in[1];
    const int*   adj_cols = (const int*)d_in[2];
    const float* adj_vals = (const float*)d_in[3];

    const size_t NH = (size_t)in_sizes[0];      // N * 128
    const int    E  = in_sizes[1];              // 1,600,000
    const int    N  = (int)(NH / HIDDEN);       // 100,000
    const size_t n4 = NH / 4;

    // d_out layout: [ total | S0 | S1 | S2 | S3 ], each NH floats
    float* T  = (float*)d_out;
    float* S0 = T + NH;
    float* S1 = S0 + NH;
    float* S2 = S1 + NH;
    float* S3 = S2 + NH;

    // Workspace layout (16B-aligned blocks)
    char* ws = (char*)d_ws;
    int*   row_ptr = (int*)ws;                       ws += ((size_t)(N + 1) * 4 + 15) & ~15ull;
    int*   cursor  = (int*)ws;                       ws += ((size_t)N * 4 + 15) & ~15ull;
    int*   csr_col = (int*)ws;                       ws += ((size_t)E * 4 + 15) & ~15ull;
    float* csr_val = (float*)ws;

    // ---- CSR build ----
    {
        int block = 256;
        int gridN = min((N + block - 1) / block, 4096);
        int gridE = min((E + block - 1) / block, 8192);
        zero_counts<<<gridN, block, 0, stream>>>(cursor, N);              // cursor as counts
        hist_kernel<<<gridE, block, 0, stream>>>(adj_rows, cursor, E);
        scan_kernel<<<1, SCAN_THREADS, 0, stream>>>(cursor, row_ptr, cursor, N);
        scatter_kernel<<<gridE, block, 0, stream>>>(adj_rows, adj_cols, adj_vals,
                                                    cursor, csr_col, csr_val, E);
    }

    // ---- S0 = item_emb ----
    {
        int block = 256;
        int grid = (int)min((n4 + block - 1) / block, (size_t)8192);
        copy_kernel<<<grid, block, 0, stream>>>((const float4*)item_emb, (float4*)S0, n4);
    }

    // ---- SpMM layers ----
    {
        int block = 256;                       // 4 waves per block
        int grid = (N * 64 + block - 1) / block;
        spmm_csr<false><<<grid, block, 0, stream>>>(row_ptr, csr_col, csr_val,
                                                    S0, S1, nullptr, nullptr, nullptr, nullptr, N);
        spmm_csr<false><<<grid, block, 0, stream>>>(row_ptr, csr_col, csr_val,
                                                    S1, S2, nullptr, nullptr, nullptr, nullptr, N);
        spmm_csr<true><<<grid, block, 0, stream>>>(row_ptr, csr_col, csr_val,
                                                   S2, S3, S0, S1, S2, T, N);
    }
}